// Round 8
// baseline (410.732 us; speedup 1.0000x reference)
//
#include <hip/hip_runtime.h>
#include <stdint.h>

#define NH 8
#define HD 48
#define CC 384
#define NN 4096
#define CK 384

typedef short short8 __attribute__((ext_vector_type(8)));
typedef float floatx4 __attribute__((ext_vector_type(4)));

__device__ inline unsigned short f32_to_bf16_bits(float f) {
    uint32_t u = __builtin_bit_cast(uint32_t, f);
    u = (u + 0x7FFFu + ((u >> 16) & 1u)) >> 16;
    return (unsigned short)u;
}
__device__ inline short8 load8(const unsigned short* p) {
    return *reinterpret_cast<const short8*>(p);
}
typedef __attribute__((address_space(1))) const void gvoid_t;
typedef __attribute__((address_space(3))) void lvoid_t;
__device__ inline void async16(const unsigned short* g, unsigned short* l) {
    __builtin_amdgcn_global_load_lds((gvoid_t*)g, (lvoid_t*)l, 16, 0, 0);
}

// ---------------- weight convert f32 -> bf16 (both weights, one launch) ----------------
__global__ __launch_bounds__(256) void k_cvt2(
    const float* __restrict__ src1, int n1,
    const float* __restrict__ src2, int n2,
    unsigned short* __restrict__ dst)
{
    int i = blockIdx.x * 256 + threadIdx.x;
    if (i >= n1 + n2) return;
    const float* s = (i < n1) ? (src1 + (size_t)i * 8) : (src2 + (size_t)(i - n1) * 8);
    unsigned short t[8];
    #pragma unroll
    for (int j = 0; j < 8; ++j) t[j] = f32_to_bf16_bits(s[j]);
    *reinterpret_cast<short8*>(dst + (size_t)i * 8) = *reinterpret_cast<short8*>(t);
}

// ---------------- QKV GEMM: 128x128, BK=64, fused x-transpose staging ----------------
// Reads x [B][C][N] f32 DIRECTLY (k_tr eliminated): per K-step, each thread loads
// 8 float4 of x (coalesced along n), converts to bf16, transpose-writes into
// As[tok][chan] (stride 72 shorts = 144 B: 16B-aligned rows, ~8-way write /
// ~2-way read banks vs 16-way at stride 64). A double-buffered in LDS (writes
// land in buf^1 after compute, x-loads issued BEFORE compute hide under 32 MFMA).
// W via global_load_lds, single buffer (L2-hot, short latency), staged between
// the two barriers. LDS 53248 B -> 3 blocks/CU.
__global__ __launch_bounds__(256) void k_qkv(
    const float* __restrict__ x,
    const unsigned short* __restrict__ W,
    unsigned short* __restrict__ QK,
    unsigned short* __restrict__ Vt)
{
    __shared__ unsigned short smem[26624];   // As0[9216] As1[9216] Ws[8192] shorts
    // XCD-aware swizzle (T1): 4608 blocks = 8 XCDs x 576 (bijective).
    int bx = blockIdx.x;
    int l  = (bx & 7) * 576 + (bx >> 3);
    int tf = l % 9, tm = l / 9;
    int m0 = tm * 128, f0 = tf * 128;
    int tid = threadIdx.x, wid = tid >> 6, lane = tid & 63;
    int l15 = lane & 15, quad = lane >> 4;
    int wm = wid & 1, wn = wid >> 1;

    int b = m0 >> 12, nb = m0 & 4095;
    const float* xb = x + (size_t)b * CC * NN + nb;
    const unsigned short* Wb = W + (size_t)f0 * CK;

    int c4  = tid >> 4;        // chan-group 0..15 (chans c4*4..+3)
    int t4a = tid & 15;        // token-group base (toks (t4a+16p)*4..+3)

    floatx4 acc[4][4] = {};
    float xr[2][4][4];         // [pass][j=chan][i=tok] (all indices compile-time)

    auto xload = [&](int kt) {
        int k0 = kt * 64;
        #pragma unroll
        for (int p = 0; p < 2; ++p) {
            int tok4 = t4a + 16 * p;
            #pragma unroll
            for (int j = 0; j < 4; ++j) {
                float4 v = *reinterpret_cast<const float4*>(
                    xb + (size_t)(k0 + c4 * 4 + j) * NN + tok4 * 4);
                const float* f = (const float*)&v;
                #pragma unroll
                for (int i = 0; i < 4; ++i) xr[p][j][i] = f[i];
            }
        }
    };
    auto xwrite = [&](int buf) {
        unsigned short* As = smem + buf * 9216;
        #pragma unroll
        for (int p = 0; p < 2; ++p) {
            int tok4 = t4a + 16 * p;
            #pragma unroll
            for (int i = 0; i < 4; ++i) {
                unsigned short u[4];
                #pragma unroll
                for (int j = 0; j < 4; ++j) u[j] = f32_to_bf16_bits(xr[p][j][i]);
                *reinterpret_cast<uint2*>(As + (tok4 * 4 + i) * 72 + c4 * 4) =
                    *reinterpret_cast<uint2*>(u);
            }
        }
    };
    auto wstage = [&](int kt) {
        int k0 = kt * 64;
        unsigned short* Ws = smem + 18432;
        #pragma unroll
        for (int i = 0; i < 4; ++i) {
            int c = i * 256 + tid;
            async16(Wb + (size_t)(c >> 3) * CK + k0 + (c & 7) * 8, Ws + (i * 256 + wid * 64) * 8);
        }
    };
    auto compute = [&](int buf) {
        unsigned short* As = smem + buf * 9216;
        unsigned short* Ws = smem + 18432;
        #pragma unroll
        for (int ks = 0; ks < 2; ++ks) {
            short8 a[4], bf[4];
            #pragma unroll
            for (int i = 0; i < 4; ++i)
                a[i] = load8(As + (wm * 64 + i * 16 + l15) * 72 + ks * 32 + quad * 8);
            #pragma unroll
            for (int j = 0; j < 4; ++j)
                bf[j] = load8(Ws + (wn * 64 + j * 16 + l15) * 64 + ks * 32 + quad * 8);
            #pragma unroll
            for (int i = 0; i < 4; ++i)
                #pragma unroll
                for (int j = 0; j < 4; ++j)
                    acc[i][j] = __builtin_amdgcn_mfma_f32_16x16x32_bf16(a[i], bf[j], acc[i][j], 0, 0, 0);
        }
    };

    // prologue: tile 0 fully staged
    xload(0);
    wstage(0);
    xwrite(0);
    __syncthreads();                       // drains W async + A ds_writes

    int cur = 0;
    #pragma unroll
    for (int kk = 0; kk < 6; ++kk) {
        if (kk < 5) xload(kk + 1);         // reg prefetch: lands under compute
        compute(cur);                      // reads As[cur] + Ws(kk)
        if (kk < 5) xwrite(cur ^ 1);       // As[cur^1]: not being read by anyone
        __syncthreads();                   // sync1: Ws reads done; As writes visible
        if (kk < 5) wstage(kk + 1);        // async overwrite Ws (safe after sync1)
        __syncthreads();                   // sync2: Ws(kk+1) staged (vmcnt 0)
        cur ^= 1;
    }

    if (tf < 6) {
        #pragma unroll
        for (int i = 0; i < 4; ++i)
            #pragma unroll
            for (int j = 0; j < 4; ++j)
                #pragma unroll
                for (int r = 0; r < 4; ++r)
                    smem[(wm * 64 + i * 16 + quad * 4 + r) * 128 + wn * 64 + j * 16 + l15] =
                        f32_to_bf16_bits(acc[i][j][r]);
        __syncthreads();
        #pragma unroll
        for (int it = 0; it < 8; ++it) {
            int c = it * 256 + tid;
            int row = c >> 4, seg = c & 15;
            *reinterpret_cast<short8*>(QK + (size_t)(m0 + row) * 768 + f0 + seg * 8) =
                load8(smem + row * 128 + seg * 8);
        }
    } else {
        #pragma unroll
        for (int i = 0; i < 4; ++i)
            #pragma unroll
            for (int j = 0; j < 4; ++j)
                #pragma unroll
                for (int r = 0; r < 4; ++r)
                    smem[(wn * 64 + j * 16 + l15) * 136 + wm * 64 + i * 16 + quad * 4 + r] =
                        f32_to_bf16_bits(acc[i][j][r]);
        __syncthreads();
        int fvb = (tf - 6) * 128;
        #pragma unroll
        for (int it = 0; it < 8; ++it) {
            int c = it * 256 + tid;
            int fl = c >> 4, seg = c & 15;
            int fv = fvb + fl;
            int h = fv / 48, d = fv - h * 48;
            *reinterpret_cast<short8*>(Vt + (((size_t)(b * 8 + h) * 48 + d) << 12) + nb + seg * 8) =
                load8(smem + fl * 136 + seg * 8);
        }
    }
}

// ---------------- block-local attention (r7 verified) ----------------
__global__ __launch_bounds__(256) void k_attn(
    const unsigned short* __restrict__ QK,     // [B*N][768]
    const unsigned short* __restrict__ Vt,     // [B][8][48][4096]
    unsigned short* __restrict__ AO)           // [B*N][384]
{
    __shared__ unsigned short ql[64][72];
    __shared__ unsigned short kl[64][72];
    __shared__ unsigned short vt[48][72];
    __shared__ float          sc[64][66];
    __shared__ unsigned short pl[64][72];

    int bx = blockIdx.x;
    int cn = bx & 63, h = (bx >> 6) & 7, b = bx >> 9;
    int n0 = cn * 64;
    int tid = threadIdx.x, wid = tid >> 6, lane = tid & 63;
    int l15 = lane & 15, quad = lane >> 4;
    int m0w = wid * 16;
    int h48 = h * 48;
    size_t b4 = (size_t)b * NN + n0;

    for (int v = tid; v < 768; v += 256) {
        int mat = v / 384;
        int idx = v - mat * 384;
        int rr = idx / 6, seg = idx - rr * 6;
        uint4 val = *reinterpret_cast<const uint4*>(QK + (b4 + rr) * 768 + mat * 384 + h48 + seg * 8);
        unsigned short* dst = mat ? &kl[rr][seg * 8] : &ql[rr][seg * 8];
        *reinterpret_cast<uint4*>(dst) = val;
    }
    {
        short8 z = {};
        int v = tid;
        if (v < 256) {
            int mat = v >> 7, rr = (v >> 1) & 63, half = v & 1;
            unsigned short* dst = mat ? &kl[rr][48 + half * 8] : &ql[rr][48 + half * 8];
            *reinterpret_cast<short8*>(dst) = z;
        }
    }
    for (int v = tid; v < 384; v += 256) {
        int d = v >> 3, seg = v & 7;
        *reinterpret_cast<uint4*>(&vt[d][seg * 8]) =
            *reinterpret_cast<const uint4*>(Vt + (((size_t)(b * 8 + h) * 48 + d) << 12) + n0 + seg * 8);
    }
    __syncthreads();

    const float scale = 0.14433756729740643f;  // 48^-0.5
    #pragma unroll
    for (int t = 0; t < 4; ++t) {
        floatx4 sacc = {};
        #pragma unroll
        for (int ks = 0; ks < 2; ++ks) {
            short8 a  = load8(&ql[m0w + l15][ks * 32 + quad * 8]);
            short8 bb = load8(&kl[t * 16 + l15][ks * 32 + quad * 8]);
            sacc = __builtin_amdgcn_mfma_f32_16x16x32_bf16(a, bb, sacc, 0, 0, 0);
        }
        #pragma unroll
        for (int r = 0; r < 4; ++r)
            sc[m0w + quad * 4 + r][t * 16 + l15] = sacc[r] * scale;
    }
    __syncthreads();

    {
        int row = m0w + l15;
        int jb  = quad * 16;
        float ev[16];
        #pragma unroll
        for (int jj = 0; jj < 16; ++jj) ev[jj] = sc[row][jb + jj];
        float m = ev[0];
        #pragma unroll
        for (int jj = 1; jj < 16; ++jj) m = fmaxf(m, ev[jj]);
        m = fmaxf(m, __shfl_xor(m, 16));
        m = fmaxf(m, __shfl_xor(m, 32));
        float s = 0.f;
        #pragma unroll
        for (int jj = 0; jj < 16; ++jj) { ev[jj] = __expf(ev[jj] - m); s += ev[jj]; }
        s += __shfl_xor(s, 16);
        s += __shfl_xor(s, 32);
        float inv = 1.0f / s;
        #pragma unroll
        for (int jj = 0; jj < 16; ++jj) pl[row][jb + jj] = f32_to_bf16_bits(ev[jj] * inv);
    }
    __syncthreads();

    #pragma unroll
    for (int t = 0; t < 3; ++t) {
        floatx4 oacc = {};
        #pragma unroll
        for (int ks = 0; ks < 2; ++ks) {
            short8 a  = load8(&pl[m0w + l15][ks * 32 + quad * 8]);
            short8 bb = load8(&vt[t * 16 + l15][ks * 32 + quad * 8]);
            oacc = __builtin_amdgcn_mfma_f32_16x16x32_bf16(a, bb, oacc, 0, 0, 0);
        }
        #pragma unroll
        for (int r = 0; r < 4; ++r)
            kl[m0w + quad * 4 + r][t * 16 + l15] = f32_to_bf16_bits(oacc[r]);
    }
    __syncthreads();

    for (int v = tid; v < 384; v += 256) {
        int rr = v / 6, seg = v - rr * 6;
        *reinterpret_cast<short8*>(AO + (b4 + rr) * CC + h48 + seg * 8) =
            load8(&kl[rr][seg * 8]);
    }
}

// ---------------- proj GEMM: BK=32, 3-buffer counted-vmcnt (r7 verified) ----------------
__global__ __launch_bounds__(256) void k_proj(
    const unsigned short* __restrict__ A,      // AO [65536][384]
    const unsigned short* __restrict__ W,      // w2 [384][384]
    const float* __restrict__ bias,            // [384] f32
    float* __restrict__ out)                   // [B][C][N] f32
{
    __shared__ unsigned short smem[24576];
    float* fs = (float*)smem;                  // [64][132] f32 staging
    int bx = blockIdx.x;
    int l  = (bx & 7) * 192 + (bx >> 3);
    int tf = l % 3, tm = l / 3;
    int m0 = tm * 128, f0 = tf * 128;
    int tid = threadIdx.x, wid = tid >> 6, lane = tid & 63;
    int l15 = lane & 15, quad = lane >> 4;
    int wm = wid & 1, wn = wid >> 1;

    const unsigned short* Ab = A + (size_t)m0 * CK;
    const unsigned short* Wb = W + (size_t)f0 * CK;

    floatx4 acc[4][4] = {};

    auto stage = [&](int kt, int buf) {
        int k0 = kt * 32;
        unsigned short* Asd = smem + buf * 8192;
        unsigned short* Wsd = Asd + 4096;
        #pragma unroll
        for (int i = 0; i < 2; ++i) {
            int c = i * 256 + tid;
            int row = c >> 2;
            int sg  = (c & 3) ^ (row & 3);
            async16(Ab + (size_t)row * CK + k0 + sg * 8, Asd + (i * 256 + wid * 64) * 8);
            async16(Wb + (size_t)row * CK + k0 + sg * 8, Wsd + (i * 256 + wid * 64) * 8);
        }
    };
    int sx = (quad ^ (l15 & 3)) * 8;
    auto compute = [&](int buf) {
        unsigned short* As = smem + buf * 8192;
        unsigned short* Ws = As + 4096;
        short8 a[4], bf[4];
        #pragma unroll
        for (int i = 0; i < 4; ++i)
            a[i] = load8(As + (wm * 64 + i * 16 + l15) * 32 + sx);
        #pragma unroll
        for (int j = 0; j < 4; ++j)
            bf[j] = load8(Ws + (wn * 64 + j * 16 + l15) * 32 + sx);
        asm volatile("s_waitcnt lgkmcnt(0)" ::: "memory");
        __builtin_amdgcn_sched_barrier(0);
        #pragma unroll
        for (int i = 0; i < 4; ++i)
            #pragma unroll
            for (int j = 0; j < 4; ++j)
                acc[i][j] = __builtin_amdgcn_mfma_f32_16x16x32_bf16(a[i], bf[j], acc[i][j], 0, 0, 0);
    };

    stage(0, 0);
    stage(1, 1);
    asm volatile("s_waitcnt vmcnt(4)" ::: "memory");
    __builtin_amdgcn_sched_barrier(0);
    __builtin_amdgcn_s_barrier();
    __builtin_amdgcn_sched_barrier(0);

    int cur = 0;
    for (int kk = 0; kk < 10; ++kk) {
        int nb3 = cur + 2; if (nb3 >= 3) nb3 -= 3;
        stage(kk + 2, nb3);
        compute(cur);
        asm volatile("s_waitcnt vmcnt(4)" ::: "memory");
        __builtin_amdgcn_sched_barrier(0);
        __builtin_amdgcn_s_barrier();
        __builtin_amdgcn_sched_barrier(0);
        cur = cur + 1 == 3 ? 0 : cur + 1;
    }
    compute(cur);
    asm volatile("s_waitcnt vmcnt(0)" ::: "memory");
    __builtin_amdgcn_sched_barrier(0);
    __builtin_amdgcn_s_barrier();
    __builtin_amdgcn_sched_barrier(0);
    cur = cur + 1 == 3 ? 0 : cur + 1;
    compute(cur);
    __syncthreads();

    int b = m0 >> 12, nb = m0 & 4095;
    #pragma unroll
    for (int hh = 0; hh < 2; ++hh) {
        if (wn == hh) {
            #pragma unroll
            for (int j = 0; j < 4; ++j) {
                float bv = bias[f0 + hh * 64 + j * 16 + l15];
                #pragma unroll
                for (int i = 0; i < 4; ++i)
                    #pragma unroll
                    for (int r = 0; r < 4; ++r)
                        fs[(j * 16 + l15) * 132 + wm * 64 + i * 16 + quad * 4 + r] =
                            acc[i][j][r] + bv;
            }
        }
        __syncthreads();
        #pragma unroll
        for (int it = 0; it < 8; ++it) {
            int c = it * 256 + tid;
            int cl = c >> 5, seg = c & 31;
            *reinterpret_cast<float4*>(
                out + (((size_t)(b * CC + f0 + hh * 64 + cl)) << 12) + nb + seg * 4) =
                *reinterpret_cast<const float4*>(fs + cl * 132 + seg * 4);
        }
        __syncthreads();
    }
}

extern "C" void kernel_launch(void* const* d_in, const int* in_sizes, int n_in,
                              void* d_out, int out_size, void* d_ws, size_t ws_size,
                              hipStream_t stream) {
    const float* x      = (const float*)d_in[0];
    const float* qkv_w  = (const float*)d_in[1];
    const float* proj_w = (const float*)d_in[2];
    const float* proj_b = (const float*)d_in[3];
    float* out = (float*)d_out;

    const size_t nX  = (size_t)16 * CC * NN;     // 25,165,824 (xT slot kept for layout stability)
    const size_t nW1 = (size_t)3 * CC * CC;      // 442,368
    const size_t nW2 = (size_t)CC * CC;          // 147,456

    unsigned short* xT  = (unsigned short*)d_ws; (void)xT;
    unsigned short* w1b = (unsigned short*)d_ws + nX;
    unsigned short* QK  = w1b + nW1 + nW2;       // [B*N][768]
    unsigned short* Vt  = QK  + (size_t)16 * NN * 768;
    unsigned short* AO  = Vt  + (size_t)16 * 8 * 48 * NN;
    unsigned short* w2b = w1b + nW1;

    k_cvt2<<<dim3((int)((nW1 + nW2) / 8 + 255) / 256, 1, 1), dim3(256), 0, stream>>>(
        qkv_w, (int)(nW1 / 8), proj_w, (int)(nW2 / 8), w1b);

    k_qkv <<<dim3(512 * 9), dim3(256), 0, stream>>>(x, w1b, QK, Vt);
    k_attn<<<dim3(16 * 8 * 64), dim3(256), 0, stream>>>(QK, Vt, AO);
    k_proj<<<dim3(512 * 3), dim3(256), 0, stream>>>(AO, w2b, proj_b, out);
}